// Round 1
// baseline (832.012 us; speedup 1.0000x reference)
//
#include <hip/hip_runtime.h>

// Problem constants (from reference setup_inputs): TP=4, T=8192, H=4096, fp32.
#define TP_ 4
#define T_  8192
#define H_  4096
#define EPS_ 1e-6f

// One block per row. 256 threads x 16 elements = 4096 = H.
// Each thread handles 4 float4 chunks, coalesced: chunk c covers elements
// (c*256 + tid)*4 .. +3.
__global__ __launch_bounds__(256) void allreduce_rmsnorm_kernel(
    const float* __restrict__ x_ranks,     // [TP, T, H]
    const float* __restrict__ residual,    // [T, H]
    const float* __restrict__ bias,        // [H]
    const float* __restrict__ norm_weight, // [H]
    float* __restrict__ out_norm,          // [T, H]
    float* __restrict__ out_inter)         // [T, H]
{
    const int row = blockIdx.x;
    const int tid = threadIdx.x;
    const size_t row_off = (size_t)row * H_;
    const size_t rank_stride = (size_t)T_ * H_;

    const float4* __restrict__ r0  = (const float4*)(x_ranks + row_off);
    const float4* __restrict__ r1  = (const float4*)(x_ranks + rank_stride     + row_off);
    const float4* __restrict__ r2  = (const float4*)(x_ranks + rank_stride * 2 + row_off);
    const float4* __restrict__ r3  = (const float4*)(x_ranks + rank_stride * 3 + row_off);
    const float4* __restrict__ res = (const float4*)(residual + row_off);
    const float4* __restrict__ b4  = (const float4*)bias;
    const float4* __restrict__ w4  = (const float4*)norm_weight;

    float4 inter[4];
    float ss = 0.0f;

    #pragma unroll
    for (int c = 0; c < 4; ++c) {
        const int idx = c * 256 + tid;
        float4 a  = r0[idx];
        float4 b  = r1[idx];
        float4 cc = r2[idx];
        float4 d  = r3[idx];
        float4 rr = res[idx];
        float4 bb = b4[idx];
        float4 v;
        v.x = a.x + b.x + cc.x + d.x + bb.x + rr.x;
        v.y = a.y + b.y + cc.y + d.y + bb.y + rr.y;
        v.z = a.z + b.z + cc.z + d.z + bb.z + rr.z;
        v.w = a.w + b.w + cc.w + d.w + bb.w + rr.w;
        inter[c] = v;
        ss += v.x * v.x + v.y * v.y + v.z * v.z + v.w * v.w;
    }

    // Wave-level reduction (wave = 64 lanes on gfx950).
    #pragma unroll
    for (int o = 32; o > 0; o >>= 1)
        ss += __shfl_down(ss, o, 64);

    __shared__ float s_partial[4];
    __shared__ float s_scale;
    const int lane = tid & 63;
    const int wave = tid >> 6;
    if (lane == 0) s_partial[wave] = ss;
    __syncthreads();
    if (tid == 0) {
        float tot = s_partial[0] + s_partial[1] + s_partial[2] + s_partial[3];
        s_scale = rsqrtf(tot * (1.0f / (float)H_) + EPS_);
    }
    __syncthreads();
    const float scale = s_scale;

    float4* __restrict__ on = (float4*)(out_norm + row_off);
    float4* __restrict__ oi = (float4*)(out_inter + row_off);

    #pragma unroll
    for (int c = 0; c < 4; ++c) {
        const int idx = c * 256 + tid;
        float4 v = inter[c];
        oi[idx] = v;
        float4 w = w4[idx];
        float4 n;
        n.x = v.x * scale * w.x;
        n.y = v.y * scale * w.y;
        n.z = v.z * scale * w.z;
        n.w = v.w * scale * w.w;
        on[idx] = n;
    }
}

extern "C" void kernel_launch(void* const* d_in, const int* in_sizes, int n_in,
                              void* d_out, int out_size, void* d_ws, size_t ws_size,
                              hipStream_t stream) {
    const float* x_ranks     = (const float*)d_in[0]; // [TP, T, H]
    const float* residual    = (const float*)d_in[1]; // [T, H]
    const float* bias        = (const float*)d_in[2]; // [H]
    const float* norm_weight = (const float*)d_in[3]; // [H]

    float* out_norm  = (float*)d_out;                      // first T*H floats
    float* out_inter = (float*)d_out + (size_t)T_ * H_;    // next T*H floats

    dim3 grid(T_);
    dim3 block(256);
    allreduce_rmsnorm_kernel<<<grid, block, 0, stream>>>(
        x_ranks, residual, bias, norm_weight, out_norm, out_inter);
}

// Round 2
// 819.700 us; speedup vs baseline: 1.0150x; 1.0150x over previous
//
#include <hip/hip_runtime.h>

// Problem constants (from reference setup_inputs): TP=4, T=8192, H=4096, fp32.
#define TP_ 4
#define T_  8192
#define H_  4096
#define EPS_ 1e-6f

// Native clang vector type so __builtin_nontemporal_{load,store} accept it.
typedef float f4 __attribute__((ext_vector_type(4)));

// One WAVE per row (no __syncthreads, no LDS): 64 lanes x 16 float4 chunks
// = 4096 elements. Cross-lane reduction is a pure shfl_xor butterfly.
// 4 waves/block -> one block covers 4 rows; grid = T/4 = 2048 blocks.
__global__ __launch_bounds__(256) void allreduce_rmsnorm_kernel(
    const float* __restrict__ x_ranks,     // [TP, T, H]
    const float* __restrict__ residual,    // [T, H]
    const float* __restrict__ bias,        // [H]
    const float* __restrict__ norm_weight, // [H]
    float* __restrict__ out_norm,          // [T, H]
    float* __restrict__ out_inter)         // [T, H]
{
    const int lane = threadIdx.x & 63;
    const int wave = threadIdx.x >> 6;
    const int row  = blockIdx.x * 4 + wave;
    const size_t row_off = (size_t)row * H_;
    const size_t rank_stride = (size_t)T_ * H_;

    const f4* __restrict__ r0 = (const f4*)(x_ranks + row_off);
    const f4* __restrict__ r1 = (const f4*)(x_ranks + rank_stride     + row_off);
    const f4* __restrict__ r2 = (const f4*)(x_ranks + rank_stride * 2 + row_off);
    const f4* __restrict__ r3 = (const f4*)(x_ranks + rank_stride * 3 + row_off);
    const f4* __restrict__ re = (const f4*)(residual + row_off);
    const f4* __restrict__ bb = (const f4*)bias;         // L2-hot (16 KB)
    const f4* __restrict__ ww = (const f4*)norm_weight;  // L2-hot (16 KB)
    f4* __restrict__ oi = (f4*)(out_inter + row_off);
    f4* __restrict__ on = (f4*)(out_norm + row_off);

    f4 inter[16];
    float ss = 0.0f;

    #pragma unroll
    for (int c = 0; c < 16; ++c) {
        const int idx = c * 64 + lane;
        f4 a0 = __builtin_nontemporal_load(r0 + idx);
        f4 a1 = __builtin_nontemporal_load(r1 + idx);
        f4 a2 = __builtin_nontemporal_load(r2 + idx);
        f4 a3 = __builtin_nontemporal_load(r3 + idx);
        f4 rr = __builtin_nontemporal_load(re + idx);
        f4 bv = bb[idx];  // reused every row -> keep cacheable
        f4 v = a0 + a1 + a2 + a3 + bv + rr;
        inter[c] = v;
        __builtin_nontemporal_store(v, oi + idx);
        ss += v.x * v.x + v.y * v.y + v.z * v.z + v.w * v.w;
    }

    // Wave-wide butterfly reduction: every lane ends with the full row sum.
    #pragma unroll
    for (int o = 1; o < 64; o <<= 1)
        ss += __shfl_xor(ss, o, 64);

    const float scale = rsqrtf(ss * (1.0f / (float)H_) + EPS_);

    #pragma unroll
    for (int c = 0; c < 16; ++c) {
        const int idx = c * 64 + lane;
        f4 w = ww[idx];  // reused every row -> keep cacheable
        f4 n = inter[c] * w;
        n *= scale;
        __builtin_nontemporal_store(n, on + idx);
    }
}

extern "C" void kernel_launch(void* const* d_in, const int* in_sizes, int n_in,
                              void* d_out, int out_size, void* d_ws, size_t ws_size,
                              hipStream_t stream) {
    const float* x_ranks     = (const float*)d_in[0]; // [TP, T, H]
    const float* residual    = (const float*)d_in[1]; // [T, H]
    const float* bias        = (const float*)d_in[2]; // [H]
    const float* norm_weight = (const float*)d_in[3]; // [H]

    float* out_norm  = (float*)d_out;                      // first T*H floats
    float* out_inter = (float*)d_out + (size_t)T_ * H_;    // next T*H floats

    dim3 grid(T_ / 4);   // 4 rows (waves) per block
    dim3 block(256);
    allreduce_rmsnorm_kernel<<<grid, block, 0, stream>>>(
        x_ranks, residual, bias, norm_weight, out_norm, out_inter);
}